// Round 10
// baseline (181.107 us; speedup 1.0000x reference)
//
#include <hip/hip_runtime.h>
#include <hip/hip_bf16.h>
#include <cstdint>

typedef unsigned short u16;
typedef __attribute__((ext_vector_type(8))) short bf16x8;
typedef __attribute__((ext_vector_type(4))) float f32x4;

#define T_SEQ 2048
#define NHEAD 16
#define HDIM  64
#define NB    2

__device__ __forceinline__ float bf2f(uint32_t h) { return __uint_as_float(h << 16); }
__device__ __forceinline__ u16 f2bf(float f) {
    uint32_t u = __float_as_uint(f);
    u += 0x7fffu + ((u >> 16) & 1u);
    return (u16)(u >> 16);
}

// async global->LDS, 16B per lane; LDS dest = wave-uniform base + lane*16
__device__ __forceinline__ void gl_lds16(const u16* g, u16* s) {
    __builtin_amdgcn_global_load_lds(
        (const __attribute__((address_space(1))) unsigned int*)g,
        (__attribute__((address_space(3))) unsigned int*)s, 16, 0, 0);
}

// Detect input dtype (parallel): bf16-packed data has low-u16 exponent fields
// clustered near 127; fp32 low halves are ~uniform mantissa bits.
__global__ void detect_dtype(const uint32_t* __restrict__ x, int* __restrict__ flag) {
    __shared__ int red[4];
    int c = 0;
#pragma unroll
    for (int j = 0; j < 4; j++) {
        uint32_t v = x[threadIdx.x * 4 + j];
        uint32_t lo = v & 0xffffu;
        uint32_t e = (lo >> 7) & 0xffu;
        if (lo != 0u && e >= 110u && e <= 135u) c++;
    }
#pragma unroll
    for (int off = 32; off; off >>= 1) c += __shfl_down(c, off);
    if ((threadIdx.x & 63) == 0) red[threadIdx.x >> 6] = c;
    __syncthreads();
    if (threadIdx.x == 0)
        *flag = (red[0] + red[1] + red[2] + red[3] > 614) ? 1 : 0;   // 1=bf16, 0=fp32
}

// vectorized conversion, 4 elements per thread
__global__ __launch_bounds__(256) void to_bf16(
    const void* __restrict__ src, u16* __restrict__ dst, int n4,
    const int* __restrict__ flag)
{
    int i = blockIdx.x * 256 + threadIdx.x;
    const int stride = gridDim.x * 256;
    if (*flag != 0) {
        const uint2* s = (const uint2*)src;
        uint2* d = (uint2*)dst;
        for (; i < n4; i += stride) d[i] = s[i];
    } else {
        const float4* s = (const float4*)src;
        for (; i < n4; i += stride) {
            float4 v = s[i];
            ushort4 o = { f2bf(v.x), f2bf(v.y), f2bf(v.z), f2bf(v.w) };
            *(ushort4*)(dst + (size_t)i * 4) = o;
        }
    }
}

// m97-pattern MFMA GEMM: C = A (MxK bf16 rm) * B^T (B NxK rm), fp32 accum.
// global_load_lds width-16 staging into unpadded [rows][64] LDS tiles with XOR
// swizzle -> conflict-free stride-64 fragment reads. 4 waves in 2x2.
// MODE 0 (128x128): scatter q [b,h,t,d] (x0.125), k [b,h,t,d], vT [b,h,d,t].
// MODE 1 (64x128): row-major C; fp32 (flag==0) or bf16 path, full-line stores.
template<int BM, int BN, int MODE>
__global__ __launch_bounds__(256, 3) void gemm_bt_mfma(
    const u16* __restrict__ A, const u16* __restrict__ B,
    int N, int K,
    u16* __restrict__ qo, u16* __restrict__ ko, u16* __restrict__ vt,
    u16* __restrict__ outb16, float* __restrict__ outf32,
    const int* __restrict__ flag)
{
    constexpr int WM = BM / 2, WN = BN / 2;
    constexpr int MI = WM / 16, NI = WN / 16;
    constexpr int IA = BM / 32, IB = BN / 32;
    constexpr int ST = (BM + BN) * 64 * 2;
    constexpr int E16 = 4 * WM * 72 * 2;
    constexpr int EF = (MODE == 1) ? 4 * WM * (WN + 4) * 4 : 0;
    constexpr int SB = (ST > E16 ? ST : E16) > EF ? (ST > E16 ? ST : E16) : EF;
    __shared__ u16 smem[SB / 2];
    u16* As = smem;            // [BM][64]
    u16* Bs = smem + BM * 64;  // [BN][64]
    const int tid = threadIdx.x;
    const int bm = blockIdx.y * BM, bn = blockIdx.x * BN;
    const int w = tid >> 6, lane = tid & 63;
    const int wm = (w >> 1) * WM, wn = (w & 1) * WN;
    const int n16 = lane & 15, quad = lane >> 4;
    const int l8 = lane >> 3, c8 = lane & 7;

    f32x4 acc[MI][NI];
#pragma unroll
    for (int mi = 0; mi < MI; mi++)
#pragma unroll
        for (int ni = 0; ni < NI; ni++) acc[mi][ni] = (f32x4){0.f, 0.f, 0.f, 0.f};

    const int KT = K >> 6;
    for (int kt = 0; kt < KT; kt++) {
        const int k0 = kt << 6;
        const int gcol = (c8 ^ l8) * 8;   // XOR swizzle: LDS chunk c holds global chunk c^(row&7)
#pragma unroll
        for (int i = 0; i < IA; i++) {
            int rowblk = (i * 4 + w) * 8;
            gl_lds16(A + (size_t)(bm + rowblk + l8) * K + k0 + gcol, As + rowblk * 64);
        }
#pragma unroll
        for (int i = 0; i < IB; i++) {
            int rowblk = (i * 4 + w) * 8;
            gl_lds16(B + (size_t)(bn + rowblk + l8) * K + k0 + gcol, Bs + rowblk * 64);
        }
        __syncthreads();
#pragma unroll
        for (int ks = 0; ks < 2; ks++) {
            bf16x8 af[MI], bfr[NI];
#pragma unroll
            for (int mi = 0; mi < MI; mi++) {
                int row = wm + mi * 16 + n16;
                af[mi] = *(const bf16x8*)(As + row * 64 + (((ks * 4 + quad) ^ (n16 & 7)) * 8));
            }
#pragma unroll
            for (int ni = 0; ni < NI; ni++) {
                int row = wn + ni * 16 + n16;
                bfr[ni] = *(const bf16x8*)(Bs + row * 64 + (((ks * 4 + quad) ^ (n16 & 7)) * 8));
            }
#pragma unroll
            for (int mi = 0; mi < MI; mi++)
#pragma unroll
                for (int ni = 0; ni < NI; ni++)
                    acc[mi][ni] = __builtin_amdgcn_mfma_f32_16x16x32_bf16(
                        af[mi], bfr[ni], acc[mi][ni], 0, 0, 0);
        }
        __syncthreads();
    }

    // Epilogues: per-wave LDS transpose -> full-line stores.
    // C/D layout: col = n16, row = quad*4 + r (HW-verified m89/m91).
    if constexpr (MODE == 0) {
        u16* ep = smem + w * (WM * 72);
        const int which = (bn + wn) >> 10;            // 0=q 1=k 2=v (wave-uniform)
        const int hq = ((bn + wn) & 1023) >> 6;
        const int bb = (bm + wm) >> 11;
        const int tb = (bm + wm) & (T_SEQ - 1);
        if (which == 2) {
#pragma unroll
            for (int mi = 0; mi < MI; mi++)
#pragma unroll
                for (int ni = 0; ni < NI; ni++)
#pragma unroll
                    for (int r = 0; r < 4; r++)
                        ep[(ni * 16 + n16) * 72 + mi * 16 + quad * 4 + r] = f2bf(acc[mi][ni][r]);
            asm volatile("s_waitcnt lgkmcnt(0)" ::: "memory");
            u16* dst = vt + ((size_t)(bb * NHEAD + hq) * HDIM) * T_SEQ + tb;
#pragma unroll
            for (int it = 0; it < 8; it++) {
                int row = it * 8 + l8, col = c8 * 8;
                bf16x8 v = *(const bf16x8*)(ep + row * 72 + col);
                *(bf16x8*)(dst + (size_t)row * T_SEQ + col) = v;
            }
        } else {
            const float sc = which ? 1.f : 0.125f;
#pragma unroll
            for (int mi = 0; mi < MI; mi++)
#pragma unroll
                for (int ni = 0; ni < NI; ni++)
#pragma unroll
                    for (int r = 0; r < 4; r++)
                        ep[(mi * 16 + quad * 4 + r) * 72 + ni * 16 + n16] = f2bf(acc[mi][ni][r] * sc);
            asm volatile("s_waitcnt lgkmcnt(0)" ::: "memory");
            u16* dst = (which ? ko : qo) + ((size_t)(bb * NHEAD + hq) * T_SEQ + tb) * HDIM;
#pragma unroll
            for (int it = 0; it < 8; it++) {
                int row = it * 8 + l8, col = c8 * 8;
                bf16x8 v = *(const bf16x8*)(ep + row * 72 + col);
                *(bf16x8*)(dst + (size_t)row * HDIM + col) = v;
            }
        }
    } else {
        if (*flag == 0) {
            float* epf = (float*)smem + w * (WM * (WN + 4));
#pragma unroll
            for (int mi = 0; mi < MI; mi++)
#pragma unroll
                for (int ni = 0; ni < NI; ni++)
#pragma unroll
                    for (int r = 0; r < 4; r++)
                        epf[(mi * 16 + quad * 4 + r) * (WN + 4) + ni * 16 + n16] = acc[mi][ni][r];
            asm volatile("s_waitcnt lgkmcnt(0)" ::: "memory");
            constexpr int LPR = WN / 4;                 // lanes per row (float4)
            constexpr int RPI = 64 / LPR;               // rows per instruction
#pragma unroll
            for (int it = 0; it < WM / RPI; it++) {
                int row = it * RPI + lane / LPR, col = (lane % LPR) * 4;
                float4 v = *(const float4*)(epf + row * (WN + 4) + col);
                *(float4*)(outf32 + (size_t)(bm + wm + row) * N + bn + wn + col) = v;
            }
        } else {
            u16* ep = smem + w * (WM * 72);
#pragma unroll
            for (int mi = 0; mi < MI; mi++)
#pragma unroll
                for (int ni = 0; ni < NI; ni++)
#pragma unroll
                    for (int r = 0; r < 4; r++)
                        ep[(mi * 16 + quad * 4 + r) * 72 + ni * 16 + n16] = f2bf(acc[mi][ni][r]);
            asm volatile("s_waitcnt lgkmcnt(0)" ::: "memory");
            constexpr int LPR = WN / 8;
            constexpr int RPI = 64 / LPR;
#pragma unroll
            for (int it = 0; it < WM / RPI; it++) {
                int row = it * RPI + lane / LPR, col = (lane % LPR) * 8;
                bf16x8 v = *(const bf16x8*)(ep + row * 72 + col);
                *(bf16x8*)(outb16 + (size_t)(bm + wm + row) * N + bn + wn + col) = v;
            }
        }
    }
}

// Split-K MFMA flash attention. Pair p: big tile qtb=31-p, small qts=p.
// Split s=0: big-tile kt in [0,16) (no diagonal) -> slot0[qtb].
// Split s=1: big-tile kt in [16,qtb] (diag) -> slot1[qtb-16], then the WHOLE
//            small tile kt in [0,qts] (diag) -> slot0[qts].
// 16 vs 17 units/block, 1024 blocks = 4/CU. Max-free softmax (p=exp(s-10))
// means partials combine by pure addition (no rescale). XCD-pinned heads.
__global__ __launch_bounds__(256, 4) void attn_mfma(
    const u16* __restrict__ qb, const u16* __restrict__ kb,
    const u16* __restrict__ vt,
    float* __restrict__ oscr0, float* __restrict__ oscr1,
    float* __restrict__ lscr0, float* __restrict__ lscr1)
{
    __shared__ u16 Ks[64 * 64];        // [t_local][d], XOR-swizzled chunks
    __shared__ u16 Vs[64 * 64];        // [d][t_local], XOR-swizzled chunks
    __shared__ u16 Plds[4][16][72];
    const int lin = blockIdx.x;        // 0..1023
    const int xcd = lin & 7;
    const int rest = lin >> 3;         // 0..127
    const int s = rest & 1;
    const int p = (rest >> 1) & 15;
    const int grp = rest >> 5;         // 0..3
    const int bh = grp * 8 + xcd;      // head pinned to xcd group
    const int qtb = 31 - p, qts = p;
    const int w = threadIdx.x >> 6, lane = threadIdx.x & 63;
    const int n16 = lane & 15, quad = lane >> 4;
    const int l8 = lane >> 3, c8 = lane & 7;
    const size_t baseK = (size_t)bh * T_SEQ * HDIM;   // [t][d]
    const size_t baseV = (size_t)bh * HDIM * T_SEQ;   // [d][t]

    bf16x8 ones;
#pragma unroll
    for (int j = 0; j < 8; j++) ones[j] = (short)0x3F80;   // bf16 1.0

    auto stage = [&](int kt) {
#pragma unroll
        for (int i = 0; i < 2; i++) {
            int rowblk = (i * 4 + w) * 8;
            int row = rowblk + l8;
            int gc = (c8 ^ l8) * 8;    // XOR swizzle
            gl_lds16(kb + baseK + (size_t)(kt * 64 + row) * HDIM + gc, Ks + rowblk * 64);
            gl_lds16(vt + baseV + (size_t)row * T_SEQ + kt * 64 + gc, Vs + rowblk * 64);
        }
    };

    auto phase = [&](int qtile, int kt0, int kt1, float* oscr, float* lscr) {
        const int qrow = qtile * 64 + w * 16;
        bf16x8 qf[2];
#pragma unroll
        for (int ks = 0; ks < 2; ks++)
            qf[ks] = *(const bf16x8*)(qb + baseK + (size_t)(qrow + n16) * HDIM + ks * 32 + quad * 8);

        f32x4 accO[4];
#pragma unroll
        for (int st = 0; st < 4; st++) accO[st] = (f32x4){0.f, 0.f, 0.f, 0.f};
        f32x4 accL = (f32x4){0.f, 0.f, 0.f, 0.f};

        stage(kt0);
        for (int kt = kt0; kt < kt1; kt++) {
            __syncthreads();   // stage(kt) complete (drains vmcnt)
            bf16x8 kf[2][4], vf[2][4];
#pragma unroll
            for (int st = 0; st < 4; st++)
#pragma unroll
                for (int ks = 0; ks < 2; ks++) {
                    int off = (st * 16 + n16) * 64 + (((ks * 4 + quad) ^ (n16 & 7)) * 8);
                    kf[ks][st] = *(const bf16x8*)(Ks + off);
                    vf[ks][st] = *(const bf16x8*)(Vs + off);
                }
            __syncthreads();   // fragments in registers; K/V LDS free
            if (kt + 1 < kt1) stage(kt + 1);   // async, lands during compute

            f32x4 S[4];
#pragma unroll
            for (int st = 0; st < 4; st++) S[st] = (f32x4){0.f, 0.f, 0.f, 0.f};
#pragma unroll
            for (int st = 0; st < 4; st++)
#pragma unroll
                for (int ks = 0; ks < 2; ks++)
                    S[st] = __builtin_amdgcn_mfma_f32_16x16x32_bf16(qf[ks], kf[ks][st], S[st], 0, 0, 0);

            if (kt == qtile) {   // diagonal tile: causal mask
                int qloc = w * 16 + quad * 4;
#pragma unroll
                for (int st = 0; st < 4; st++) {
                    int kloc = st * 16 + n16;
#pragma unroll
                    for (int r = 0; r < 4; r++)
                        if (kloc > qloc + r) S[st][r] = -INFINITY;
                }
            }

            // p = exp(s - 10) = exp2(1.4427*s - 14.427); bf16 by truncation
#pragma unroll
            for (int st = 0; st < 4; st++)
#pragma unroll
                for (int r = 0; r < 4; r++) {
                    float pv = exp2f(__builtin_fmaf(S[st][r], 1.44269504f, -14.4269504f));
                    Plds[w][quad * 4 + r][st * 16 + n16] = (u16)(__float_as_uint(pv) >> 16);
                }
            asm volatile("s_waitcnt lgkmcnt(0)" ::: "memory");
            bf16x8 pf[2];
#pragma unroll
            for (int ks = 0; ks < 2; ks++)
                pf[ks] = *(const bf16x8*)(&Plds[w][n16][ks * 32 + quad * 8]);

#pragma unroll
            for (int st = 0; st < 4; st++)
#pragma unroll
                for (int ks = 0; ks < 2; ks++)
                    accO[st] = __builtin_amdgcn_mfma_f32_16x16x32_bf16(pf[ks], vf[ks][st], accO[st], 0, 0, 0);
#pragma unroll
            for (int ks = 0; ks < 2; ks++)
                accL = __builtin_amdgcn_mfma_f32_16x16x32_bf16(pf[ks], ones, accL, 0, 0, 0);
        }

        // partial store: oscr tile is [64 rows][64 cols] fp32
#pragma unroll
        for (int st = 0; st < 4; st++)
#pragma unroll
            for (int r = 0; r < 4; r++)
                oscr[(w * 16 + quad * 4 + r) * 64 + st * 16 + n16] = accO[st][r];
        if (n16 == 0)
#pragma unroll
            for (int r = 0; r < 4; r++)
                lscr[w * 16 + quad * 4 + r] = accL[r];
    };

    if (s == 0) {
        phase(qtb, 0, 16,
              oscr0 + ((size_t)bh * 32 + qtb) * 4096,
              lscr0 + ((size_t)bh * 32 + qtb) * 64);
    } else {
        phase(qtb, 16, qtb + 1,
              oscr1 + ((size_t)bh * 16 + (qtb - 16)) * 4096,
              lscr1 + ((size_t)bh * 16 + (qtb - 16)) * 64);
        phase(qts, 0, qts + 1,
              oscr0 + ((size_t)bh * 32 + qts) * 4096,
              lscr0 + ((size_t)bh * 32 + qts) * 64);
    }
}

// Combine split-K partials: out = (o0 [+ o1]) / (l0 [+ l1]), write bf16 to
// obuf (B,T,C). One block per (bh, qt); thread t>>2 = row, (t&3)*16 = colbase.
__global__ __launch_bounds__(256) void attn_combine(
    const float* __restrict__ oscr0, const float* __restrict__ oscr1,
    const float* __restrict__ lscr0, const float* __restrict__ lscr1,
    u16* __restrict__ ob)
{
    const int bhqt = blockIdx.x;
    const int bh = bhqt >> 5, qt = bhqt & 31;
    const int b = bh >> 4, h = bh & 15;
    const int t = threadIdx.x >> 2, cb = (threadIdx.x & 3) * 16;

    const float* o0 = oscr0 + ((size_t)bh * 32 + qt) * 4096 + t * 64 + cb;
    float l = lscr0[((size_t)bh * 32 + qt) * 64 + t];
    float4 v[4];
#pragma unroll
    for (int j = 0; j < 4; j++) v[j] = *(const float4*)(o0 + j * 4);
    if (qt >= 16) {
        const float* o1 = oscr1 + ((size_t)bh * 16 + (qt - 16)) * 4096 + t * 64 + cb;
        l += lscr1[((size_t)bh * 16 + (qt - 16)) * 64 + t];
#pragma unroll
        for (int j = 0; j < 4; j++) {
            float4 u = *(const float4*)(o1 + j * 4);
            v[j].x += u.x; v[j].y += u.y; v[j].z += u.z; v[j].w += u.w;
        }
    }
    float inv = 1.f / l;
    u16* dst = ob + ((size_t)(b * T_SEQ + qt * 64 + t)) * 1024 + h * HDIM + cb;
#pragma unroll
    for (int j = 0; j < 4; j++) {
        ushort4 o = { f2bf(v[j].x * inv), f2bf(v[j].y * inv),
                      f2bf(v[j].z * inv), f2bf(v[j].w * inv) };
        *(ushort4*)(dst + j * 4) = o;
    }
}

extern "C" void kernel_launch(void* const* d_in, const int* in_sizes, int n_in,
                              void* d_out, int out_size, void* d_ws, size_t ws_size,
                              hipStream_t stream) {
    const void* x    = d_in[0];   // (2,2048,1024)
    const void* Wqkv = d_in[1];   // (3072,1024)
    const void* Wout = d_in[2];   // (1024,1024)

    const int Mtok = NB * T_SEQ;                                  // 4096
    const size_t n_x    = (size_t)Mtok * 1024;
    const size_t n_wqkv = (size_t)3072 * 1024;
    const size_t n_wout = (size_t)1024 * 1024;
    const size_t qkv_elems = (size_t)NB * NHEAD * T_SEQ * HDIM;   // 4,194,304

    u16* xb    = (u16*)d_ws;
    u16* wqkvb = xb + n_x;
    u16* woutb = wqkvb + n_wqkv;
    u16* qb    = woutb + n_wout;
    u16* kb    = qb + qkv_elems;
    u16* vt    = kb + qkv_elems;   // V stored transposed [b,h,d,t]
    u16* obuf  = vt + qkv_elems;
    float* oscr0 = (float*)(obuf + qkv_elems);          // [32][32][4096]
    float* oscr1 = oscr0 + (size_t)32 * 32 * 4096;      // [32][16][4096]
    float* lscr0 = oscr1 + (size_t)32 * 16 * 4096;      // [32][32][64]
    float* lscr1 = lscr0 + (size_t)32 * 32 * 64;        // [32][16][64]
    int* flag  = (int*)(lscr1 + (size_t)32 * 16 * 64);

    detect_dtype<<<1, 256, 0, stream>>>((const uint32_t*)x, flag);

    to_bf16<<<1024, 256, 0, stream>>>(x,    xb,    (int)(n_x / 4),    flag);
    to_bf16<<<1024, 256, 0, stream>>>(Wqkv, wqkvb, (int)(n_wqkv / 4), flag);
    to_bf16<<<512,  256, 0, stream>>>(Wout, woutb, (int)(n_wout / 4), flag);

    gemm_bt_mfma<128, 128, 0><<<dim3(3072 / 128, Mtok / 128), 256, 0, stream>>>(
        xb, wqkvb, 3072, 1024, qb, kb, vt, nullptr, nullptr, flag);

    attn_mfma<<<dim3(NB * NHEAD * (T_SEQ / 128) * 2), 256, 0, stream>>>(
        qb, kb, vt, oscr0, oscr1, lscr0, lscr1);

    attn_combine<<<dim3(NB * NHEAD * (T_SEQ / 64)), 256, 0, stream>>>(
        oscr0, oscr1, lscr0, lscr1, obuf);

    gemm_bt_mfma<64, 128, 1><<<dim3(1024 / 128, Mtok / 64), 256, 0, stream>>>(
        obuf, woutb, 1024, 1024, nullptr, nullptr, nullptr,
        (u16*)d_out, (float*)d_out, flag);
}

// Round 11
// 174.999 us; speedup vs baseline: 1.0349x; 1.0349x over previous
//
#include <hip/hip_runtime.h>
#include <hip/hip_bf16.h>
#include <cstdint>

typedef unsigned short u16;
typedef __attribute__((ext_vector_type(8))) short bf16x8;
typedef __attribute__((ext_vector_type(4))) float f32x4;

#define T_SEQ 2048
#define NHEAD 16
#define HDIM  64
#define NB    2

__device__ __forceinline__ float bf2f(uint32_t h) { return __uint_as_float(h << 16); }
__device__ __forceinline__ u16 f2bf(float f) {
    uint32_t u = __float_as_uint(f);
    u += 0x7fffu + ((u >> 16) & 1u);
    return (u16)(u >> 16);
}

// async global->LDS, 16B per lane; LDS dest = wave-uniform base + lane*16
__device__ __forceinline__ void gl_lds16(const u16* g, u16* s) {
    __builtin_amdgcn_global_load_lds(
        (const __attribute__((address_space(1))) unsigned int*)g,
        (__attribute__((address_space(3))) unsigned int*)s, 16, 0, 0);
}

// Detect input dtype (parallel): bf16-packed data has low-u16 exponent fields
// clustered near 127; fp32 low halves are ~uniform mantissa bits.
__global__ void detect_dtype(const uint32_t* __restrict__ x, int* __restrict__ flag) {
    __shared__ int red[4];
    int c = 0;
#pragma unroll
    for (int j = 0; j < 4; j++) {
        uint32_t v = x[threadIdx.x * 4 + j];
        uint32_t lo = v & 0xffffu;
        uint32_t e = (lo >> 7) & 0xffu;
        if (lo != 0u && e >= 110u && e <= 135u) c++;
    }
#pragma unroll
    for (int off = 32; off; off >>= 1) c += __shfl_down(c, off);
    if ((threadIdx.x & 63) == 0) red[threadIdx.x >> 6] = c;
    __syncthreads();
    if (threadIdx.x == 0)
        *flag = (red[0] + red[1] + red[2] + red[3] > 614) ? 1 : 0;   // 1=bf16, 0=fp32
}

// vectorized conversion, 4 elements per thread
__global__ __launch_bounds__(256) void to_bf16(
    const void* __restrict__ src, u16* __restrict__ dst, int n4,
    const int* __restrict__ flag)
{
    int i = blockIdx.x * 256 + threadIdx.x;
    const int stride = gridDim.x * 256;
    if (*flag != 0) {
        const uint2* s = (const uint2*)src;
        uint2* d = (uint2*)dst;
        for (; i < n4; i += stride) d[i] = s[i];
    } else {
        const float4* s = (const float4*)src;
        for (; i < n4; i += stride) {
            float4 v = s[i];
            ushort4 o = { f2bf(v.x), f2bf(v.y), f2bf(v.z), f2bf(v.w) };
            *(ushort4*)(dst + (size_t)i * 4) = o;
        }
    }
}

// m97-pattern MFMA GEMM: C = A (MxK bf16 rm) * B^T (B NxK rm), fp32 accum.
// global_load_lds width-16 staging into unpadded [rows][64] LDS tiles with XOR
// swizzle -> conflict-free stride-64 fragment reads. 4 waves in 2x2.
// MODE 0 (128x128): scatter q [b,h,t,d] (x0.125), k [b,h,t,d], vT [b,h,d,t].
// MODE 1 (64x128): row-major C; fp32 (flag==0) or bf16 path, full-line stores.
template<int BM, int BN, int MODE, int MINW>
__global__ __launch_bounds__(256, MINW) void gemm_bt_mfma(
    const u16* __restrict__ A, const u16* __restrict__ B,
    int N, int K,
    u16* __restrict__ qo, u16* __restrict__ ko, u16* __restrict__ vt,
    u16* __restrict__ outb16, float* __restrict__ outf32,
    const int* __restrict__ flag)
{
    constexpr int WM = BM / 2, WN = BN / 2;
    constexpr int MI = WM / 16, NI = WN / 16;
    constexpr int IA = BM / 32, IB = BN / 32;
    constexpr int ST = (BM + BN) * 64 * 2;
    constexpr int E16 = 4 * WM * 72 * 2;
    constexpr int EF = (MODE == 1) ? 4 * WM * (WN + 4) * 4 : 0;
    constexpr int SB = (ST > E16 ? ST : E16) > EF ? (ST > E16 ? ST : E16) : EF;
    __shared__ u16 smem[SB / 2];
    u16* As = smem;            // [BM][64]
    u16* Bs = smem + BM * 64;  // [BN][64]
    const int tid = threadIdx.x;
    const int bm = blockIdx.y * BM, bn = blockIdx.x * BN;
    const int w = tid >> 6, lane = tid & 63;
    const int wm = (w >> 1) * WM, wn = (w & 1) * WN;
    const int n16 = lane & 15, quad = lane >> 4;
    const int l8 = lane >> 3, c8 = lane & 7;

    f32x4 acc[MI][NI];
#pragma unroll
    for (int mi = 0; mi < MI; mi++)
#pragma unroll
        for (int ni = 0; ni < NI; ni++) acc[mi][ni] = (f32x4){0.f, 0.f, 0.f, 0.f};

    const int KT = K >> 6;
    for (int kt = 0; kt < KT; kt++) {
        const int k0 = kt << 6;
        const int gcol = (c8 ^ l8) * 8;   // XOR swizzle: LDS chunk c holds global chunk c^(row&7)
#pragma unroll
        for (int i = 0; i < IA; i++) {
            int rowblk = (i * 4 + w) * 8;
            gl_lds16(A + (size_t)(bm + rowblk + l8) * K + k0 + gcol, As + rowblk * 64);
        }
#pragma unroll
        for (int i = 0; i < IB; i++) {
            int rowblk = (i * 4 + w) * 8;
            gl_lds16(B + (size_t)(bn + rowblk + l8) * K + k0 + gcol, Bs + rowblk * 64);
        }
        __syncthreads();
#pragma unroll
        for (int ks = 0; ks < 2; ks++) {
            bf16x8 af[MI], bfr[NI];
#pragma unroll
            for (int mi = 0; mi < MI; mi++) {
                int row = wm + mi * 16 + n16;
                af[mi] = *(const bf16x8*)(As + row * 64 + (((ks * 4 + quad) ^ (n16 & 7)) * 8));
            }
#pragma unroll
            for (int ni = 0; ni < NI; ni++) {
                int row = wn + ni * 16 + n16;
                bfr[ni] = *(const bf16x8*)(Bs + row * 64 + (((ks * 4 + quad) ^ (n16 & 7)) * 8));
            }
#pragma unroll
            for (int mi = 0; mi < MI; mi++)
#pragma unroll
                for (int ni = 0; ni < NI; ni++)
                    acc[mi][ni] = __builtin_amdgcn_mfma_f32_16x16x32_bf16(
                        af[mi], bfr[ni], acc[mi][ni], 0, 0, 0);
        }
        __syncthreads();
    }

    // Epilogues: per-wave LDS transpose -> full-line stores.
    // C/D layout: col = n16, row = quad*4 + r (HW-verified m89/m91).
    if constexpr (MODE == 0) {
        u16* ep = smem + w * (WM * 72);
        const int which = (bn + wn) >> 10;            // 0=q 1=k 2=v (wave-uniform)
        const int hq = ((bn + wn) & 1023) >> 6;
        const int bb = (bm + wm) >> 11;
        const int tb = (bm + wm) & (T_SEQ - 1);
        if (which == 2) {
#pragma unroll
            for (int mi = 0; mi < MI; mi++)
#pragma unroll
                for (int ni = 0; ni < NI; ni++)
#pragma unroll
                    for (int r = 0; r < 4; r++)
                        ep[(ni * 16 + n16) * 72 + mi * 16 + quad * 4 + r] = f2bf(acc[mi][ni][r]);
            asm volatile("s_waitcnt lgkmcnt(0)" ::: "memory");
            u16* dst = vt + ((size_t)(bb * NHEAD + hq) * HDIM) * T_SEQ + tb;
#pragma unroll
            for (int it = 0; it < 8; it++) {
                int row = it * 8 + l8, col = c8 * 8;
                bf16x8 v = *(const bf16x8*)(ep + row * 72 + col);
                *(bf16x8*)(dst + (size_t)row * T_SEQ + col) = v;
            }
        } else {
            const float sc = which ? 1.f : 0.125f;
#pragma unroll
            for (int mi = 0; mi < MI; mi++)
#pragma unroll
                for (int ni = 0; ni < NI; ni++)
#pragma unroll
                    for (int r = 0; r < 4; r++)
                        ep[(mi * 16 + quad * 4 + r) * 72 + ni * 16 + n16] = f2bf(acc[mi][ni][r] * sc);
            asm volatile("s_waitcnt lgkmcnt(0)" ::: "memory");
            u16* dst = (which ? ko : qo) + ((size_t)(bb * NHEAD + hq) * T_SEQ + tb) * HDIM;
#pragma unroll
            for (int it = 0; it < 8; it++) {
                int row = it * 8 + l8, col = c8 * 8;
                bf16x8 v = *(const bf16x8*)(ep + row * 72 + col);
                *(bf16x8*)(dst + (size_t)row * HDIM + col) = v;
            }
        }
    } else {
        if (*flag == 0) {
            float* epf = (float*)smem + w * (WM * (WN + 4));
#pragma unroll
            for (int mi = 0; mi < MI; mi++)
#pragma unroll
                for (int ni = 0; ni < NI; ni++)
#pragma unroll
                    for (int r = 0; r < 4; r++)
                        epf[(mi * 16 + quad * 4 + r) * (WN + 4) + ni * 16 + n16] = acc[mi][ni][r];
            asm volatile("s_waitcnt lgkmcnt(0)" ::: "memory");
            constexpr int LPR = WN / 4;                 // lanes per row (float4)
            constexpr int RPI = 64 / LPR;               // rows per instruction
#pragma unroll
            for (int it = 0; it < WM / RPI; it++) {
                int row = it * RPI + lane / LPR, col = (lane % LPR) * 4;
                float4 v = *(const float4*)(epf + row * (WN + 4) + col);
                *(float4*)(outf32 + (size_t)(bm + wm + row) * N + bn + wn + col) = v;
            }
        } else {
            u16* ep = smem + w * (WM * 72);
#pragma unroll
            for (int mi = 0; mi < MI; mi++)
#pragma unroll
                for (int ni = 0; ni < NI; ni++)
#pragma unroll
                    for (int r = 0; r < 4; r++)
                        ep[(mi * 16 + quad * 4 + r) * 72 + ni * 16 + n16] = f2bf(acc[mi][ni][r]);
            asm volatile("s_waitcnt lgkmcnt(0)" ::: "memory");
            constexpr int LPR = WN / 8;
            constexpr int RPI = 64 / LPR;
#pragma unroll
            for (int it = 0; it < WM / RPI; it++) {
                int row = it * RPI + lane / LPR, col = (lane % LPR) * 8;
                bf16x8 v = *(const bf16x8*)(ep + row * 72 + col);
                *(bf16x8*)(outb16 + (size_t)(bm + wm + row) * N + bn + wn + col) = v;
            }
        }
    }
}

// MFMA flash attention: paired q-tiles (p, 31-p) sharing one staged K/V
// stream, XCD-pinned heads, max-free softmax (p=exp(s-10), cancels in o/l),
// denominators via mfma(P,1). SOFTWARE-PIPELINED: PV(kt-1) executes during
// iteration kt using register-carried pf/vf_prev, hiding the P LDS
// round-trip latency under independent MFMAs.
__global__ __launch_bounds__(256, 2) void attn_mfma(
    const u16* __restrict__ qb, const u16* __restrict__ kb,
    const u16* __restrict__ vt, u16* __restrict__ ob)
{
    __shared__ u16 Ks[64 * 64];        // [t_local][d], XOR-swizzled chunks
    __shared__ u16 Vs[64 * 64];        // [d][t_local], XOR-swizzled chunks
    __shared__ u16 PldsB[4][16][72];   // big-tile P
    __shared__ u16 PldsS[4][16][72];   // small-tile P
    const int lin = blockIdx.x;        // 0..511
    const int xcd = lin & 7;
    const int rest = lin >> 3;         // 0..63
    const int p = rest & 15;
    const int grp = rest >> 4;         // 0..3
    const int bh = grp * 8 + xcd;      // head pinned to xcd group
    const int qtb = 31 - p, qts = p;   // big / small q-tile
    const int w = threadIdx.x >> 6, lane = threadIdx.x & 63;
    const int n16 = lane & 15, quad = lane >> 4;
    const int l8 = lane >> 3, c8 = lane & 7;
    const size_t baseK = (size_t)bh * T_SEQ * HDIM;   // [t][d]
    const size_t baseV = (size_t)bh * HDIM * T_SEQ;   // [d][t]
    const int b = bh >> 4, h = bh & 15;

    bf16x8 ones;
#pragma unroll
    for (int j = 0; j < 8; j++) ones[j] = (short)0x3F80;   // bf16 1.0

    auto stage = [&](int kt) {
#pragma unroll
        for (int i = 0; i < 2; i++) {
            int rowblk = (i * 4 + w) * 8;
            int row = rowblk + l8;
            int gc = (c8 ^ l8) * 8;    // XOR swizzle
            gl_lds16(kb + baseK + (size_t)(kt * 64 + row) * HDIM + gc, Ks + rowblk * 64);
            gl_lds16(vt + baseV + (size_t)row * T_SEQ + kt * 64 + gc, Vs + rowblk * 64);
        }
    };

    const int qrowb = qtb * 64 + w * 16, qrows = qts * 64 + w * 16;
    bf16x8 qfb[2], qfs[2];
#pragma unroll
    for (int ks = 0; ks < 2; ks++) {
        qfb[ks] = *(const bf16x8*)(qb + baseK + (size_t)(qrowb + n16) * HDIM + ks * 32 + quad * 8);
        qfs[ks] = *(const bf16x8*)(qb + baseK + (size_t)(qrows + n16) * HDIM + ks * 32 + quad * 8);
    }

    f32x4 accOb[4], accOs[4];
#pragma unroll
    for (int st = 0; st < 4; st++) {
        accOb[st] = (f32x4){0.f, 0.f, 0.f, 0.f};
        accOs[st] = (f32x4){0.f, 0.f, 0.f, 0.f};
    }
    f32x4 accLb = (f32x4){0.f, 0.f, 0.f, 0.f};
    f32x4 accLs = (f32x4){0.f, 0.f, 0.f, 0.f};

    bf16x8 pfb[2], pfs[2], vfp[2][4];   // carried across iterations

    stage(0);
    for (int kt = 0; kt <= qtb; kt++) {
        __syncthreads();   // stage(kt) complete (drains vmcnt)

        bf16x8 kf[2][4], vf[2][4];
#pragma unroll
        for (int st = 0; st < 4; st++)
#pragma unroll
            for (int ks = 0; ks < 2; ks++) {
                int off = (st * 16 + n16) * 64 + (((ks * 4 + quad) ^ (n16 & 7)) * 8);
                kf[ks][st] = *(const bf16x8*)(Ks + off);
                vf[ks][st] = *(const bf16x8*)(Vs + off);
            }
        __syncthreads();   // fragments in registers; K/V LDS free

        if (kt < qtb) stage(kt + 1);   // async, lands during compute below

        // QK for both tiles (independent MFMAs)
        f32x4 Sb[4], Ss[4];
#pragma unroll
        for (int st = 0; st < 4; st++) {
            Sb[st] = (f32x4){0.f, 0.f, 0.f, 0.f};
            Ss[st] = (f32x4){0.f, 0.f, 0.f, 0.f};
        }
#pragma unroll
        for (int st = 0; st < 4; st++)
#pragma unroll
            for (int ks = 0; ks < 2; ks++)
                Sb[st] = __builtin_amdgcn_mfma_f32_16x16x32_bf16(qfb[ks], kf[ks][st], Sb[st], 0, 0, 0);
        if (kt <= qts)
#pragma unroll
            for (int st = 0; st < 4; st++)
#pragma unroll
                for (int ks = 0; ks < 2; ks++)
                    Ss[st] = __builtin_amdgcn_mfma_f32_16x16x32_bf16(qfs[ks], kf[ks][st], Ss[st], 0, 0, 0);

        // deferred PV(kt-1) — register-only, overlaps exp/P-round-trip below
        if (kt > 0) {
#pragma unroll
            for (int st = 0; st < 4; st++)
#pragma unroll
                for (int ks = 0; ks < 2; ks++)
                    accOb[st] = __builtin_amdgcn_mfma_f32_16x16x32_bf16(pfb[ks], vfp[ks][st], accOb[st], 0, 0, 0);
#pragma unroll
            for (int ks = 0; ks < 2; ks++)
                accLb = __builtin_amdgcn_mfma_f32_16x16x32_bf16(pfb[ks], ones, accLb, 0, 0, 0);
            if (kt - 1 <= qts) {
#pragma unroll
                for (int st = 0; st < 4; st++)
#pragma unroll
                    for (int ks = 0; ks < 2; ks++)
                        accOs[st] = __builtin_amdgcn_mfma_f32_16x16x32_bf16(pfs[ks], vfp[ks][st], accOs[st], 0, 0, 0);
#pragma unroll
                for (int ks = 0; ks < 2; ks++)
                    accLs = __builtin_amdgcn_mfma_f32_16x16x32_bf16(pfs[ks], ones, accLs, 0, 0, 0);
            }
        }

        // softmax big: p = exp(s-10) = exp2(1.4427*s - 14.427); bf16 truncation
        if (kt == qtb) {
            int qloc = w * 16 + quad * 4;
#pragma unroll
            for (int st = 0; st < 4; st++) {
                int kloc = st * 16 + n16;
#pragma unroll
                for (int r = 0; r < 4; r++)
                    if (kloc > qloc + r) Sb[st][r] = -INFINITY;
            }
        }
#pragma unroll
        for (int st = 0; st < 4; st++)
#pragma unroll
            for (int r = 0; r < 4; r++) {
                float pv = exp2f(__builtin_fmaf(Sb[st][r], 1.44269504f, -14.4269504f));
                PldsB[w][quad * 4 + r][st * 16 + n16] = (u16)(__float_as_uint(pv) >> 16);
            }
        if (kt <= qts) {
            if (kt == qts) {
                int qloc = w * 16 + quad * 4;
#pragma unroll
                for (int st = 0; st < 4; st++) {
                    int kloc = st * 16 + n16;
#pragma unroll
                    for (int r = 0; r < 4; r++)
                        if (kloc > qloc + r) Ss[st][r] = -INFINITY;
                }
            }
#pragma unroll
            for (int st = 0; st < 4; st++)
#pragma unroll
                for (int r = 0; r < 4; r++) {
                    float pv = exp2f(__builtin_fmaf(Ss[st][r], 1.44269504f, -14.4269504f));
                    PldsS[w][quad * 4 + r][st * 16 + n16] = (u16)(__float_as_uint(pv) >> 16);
                }
        }
        asm volatile("s_waitcnt lgkmcnt(0)" ::: "memory");
#pragma unroll
        for (int ks = 0; ks < 2; ks++)
            pfb[ks] = *(const bf16x8*)(&PldsB[w][n16][ks * 32 + quad * 8]);
        if (kt <= qts)
#pragma unroll
            for (int ks = 0; ks < 2; ks++)
                pfs[ks] = *(const bf16x8*)(&PldsS[w][n16][ks * 32 + quad * 8]);
#pragma unroll
        for (int st = 0; st < 4; st++)
#pragma unroll
            for (int ks = 0; ks < 2; ks++)
                vfp[ks][st] = vf[ks][st];
    }

    // final PV(qtb) for the big tile (small tile's last PV ran in-loop since
    // qts+1 <= qtb for all p in [0,16))
#pragma unroll
    for (int st = 0; st < 4; st++)
#pragma unroll
        for (int ks = 0; ks < 2; ks++)
            accOb[st] = __builtin_amdgcn_mfma_f32_16x16x32_bf16(pfb[ks], vfp[ks][st], accOb[st], 0, 0, 0);
#pragma unroll
    for (int ks = 0; ks < 2; ks++)
        accLb = __builtin_amdgcn_mfma_f32_16x16x32_bf16(pfb[ks], ones, accLb, 0, 0, 0);

    // epilogues: normalize, transpose via PldsB (wave-private), line stores
    __syncthreads();   // everyone past the K-loop; Plds reusable
#pragma unroll
    for (int r = 0; r < 4; r++) {
        float inv = 1.f / accLb[r];
#pragma unroll
        for (int st = 0; st < 4; st++)
            PldsB[w][quad * 4 + r][st * 16 + n16] = f2bf(accOb[st][r] * inv);
    }
#pragma unroll
    for (int r = 0; r < 4; r++) {
        float inv = 1.f / accLs[r];
#pragma unroll
        for (int st = 0; st < 4; st++)
            PldsS[w][quad * 4 + r][st * 16 + n16] = f2bf(accOs[st][r] * inv);
    }
    asm volatile("s_waitcnt lgkmcnt(0)" ::: "memory");
    u16* dstb = ob + ((size_t)(b * T_SEQ + qrowb)) * 1024 + h * HDIM;
    u16* dsts = ob + ((size_t)(b * T_SEQ + qrows)) * 1024 + h * HDIM;
#pragma unroll
    for (int it = 0; it < 2; it++) {
        int row = it * 8 + l8, col = c8 * 8;
        bf16x8 v1 = *(const bf16x8*)(&PldsB[w][row][col]);
        *(bf16x8*)(dstb + (size_t)row * 1024 + col) = v1;
        bf16x8 v2 = *(const bf16x8*)(&PldsS[w][row][col]);
        *(bf16x8*)(dsts + (size_t)row * 1024 + col) = v2;
    }
}

extern "C" void kernel_launch(void* const* d_in, const int* in_sizes, int n_in,
                              void* d_out, int out_size, void* d_ws, size_t ws_size,
                              hipStream_t stream) {
    const void* x    = d_in[0];   // (2,2048,1024)
    const void* Wqkv = d_in[1];   // (3072,1024)
    const void* Wout = d_in[2];   // (1024,1024)

    const int Mtok = NB * T_SEQ;                                  // 4096
    const size_t n_x    = (size_t)Mtok * 1024;
    const size_t n_wqkv = (size_t)3072 * 1024;
    const size_t n_wout = (size_t)1024 * 1024;
    const size_t qkv_elems = (size_t)NB * NHEAD * T_SEQ * HDIM;   // 4,194,304

    u16* xb    = (u16*)d_ws;
    u16* wqkvb = xb + n_x;
    u16* woutb = wqkvb + n_wqkv;
    u16* qb    = woutb + n_wout;
    u16* kb    = qb + qkv_elems;
    u16* vt    = kb + qkv_elems;   // V stored transposed [b,h,d,t]
    u16* obuf  = vt + qkv_elems;
    int* flag  = (int*)(obuf + qkv_elems);

    detect_dtype<<<1, 256, 0, stream>>>((const uint32_t*)x, flag);

    to_bf16<<<1024, 256, 0, stream>>>(x,    xb,    (int)(n_x / 4),    flag);
    to_bf16<<<1024, 256, 0, stream>>>(Wqkv, wqkvb, (int)(n_wqkv / 4), flag);
    to_bf16<<<512,  256, 0, stream>>>(Wout, woutb, (int)(n_wout / 4), flag);

    gemm_bt_mfma<128, 128, 0, 3><<<dim3(3072 / 128, Mtok / 128), 256, 0, stream>>>(
        xb, wqkvb, 3072, 1024, qb, kb, vt, nullptr, nullptr, flag);

    attn_mfma<<<dim3(NB * NHEAD * (T_SEQ / 128)), 256, 0, stream>>>(qb, kb, vt, obuf);

    gemm_bt_mfma<64, 128, 1, 4><<<dim3(1024 / 128, Mtok / 64), 256, 0, stream>>>(
        obuf, woutb, 1024, 1024, nullptr, nullptr, nullptr,
        (u16*)d_out, (float*)d_out, flag);
}